// Round 8
// baseline (167.732 us; speedup 1.0000x reference)
//
#include <hip/hip_runtime.h>
#include <math.h>

#define NT   196
#define EMB  256
#define NH   8
#define DH   32
#define HID  1024
#define EPSV 1e-5f

// 4x4-register-blocked K-panel: 1 float4 W load + 1 broadcast b128 X read +
// 16 fma per iter. Threads: cq = t&63 (col quad), ks = t>>6 (K split of 4).
// unroll 16 => 16 outstanding dwordx4 loads to hide L2/HBM latency.
#define GEMM_PANEL(Wptr, ldw, xsT, pp, cq, ks, KITER)                          \
    {                                                                          \
        const float* Wb = (Wptr);                                              \
        float4 a0 = {0,0,0,0}, a1 = a0, a2 = a0, a3 = a0;                      \
        _Pragma("unroll 16")                                                   \
        for (int kk = (ks) * (KITER); kk < (ks) * (KITER) + (KITER); kk++) {   \
            float4 w4 = *(const float4*)&Wb[kk * (ldw)];                       \
            float4 xr = *(const float4*)&(xsT)[kk * 4];                        \
            a0.x = fmaf(xr.x, w4.x, a0.x); a0.y = fmaf(xr.x, w4.y, a0.y);      \
            a0.z = fmaf(xr.x, w4.z, a0.z); a0.w = fmaf(xr.x, w4.w, a0.w);      \
            a1.x = fmaf(xr.y, w4.x, a1.x); a1.y = fmaf(xr.y, w4.y, a1.y);      \
            a1.z = fmaf(xr.y, w4.z, a1.z); a1.w = fmaf(xr.y, w4.w, a1.w);      \
            a2.x = fmaf(xr.z, w4.x, a2.x); a2.y = fmaf(xr.z, w4.y, a2.y);      \
            a2.z = fmaf(xr.z, w4.z, a2.z); a2.w = fmaf(xr.z, w4.w, a2.w);      \
            a3.x = fmaf(xr.w, w4.x, a3.x); a3.y = fmaf(xr.w, w4.y, a3.y);      \
            a3.z = fmaf(xr.w, w4.z, a3.z); a3.w = fmaf(xr.w, w4.w, a3.w);      \
        }                                                                      \
        *(float4*)&(pp)[((ks) * 4 + 0) * 256 + (cq) * 4] = a0;                 \
        *(float4*)&(pp)[((ks) * 4 + 1) * 256 + (cq) * 4] = a1;                 \
        *(float4*)&(pp)[((ks) * 4 + 2) * 256 + (cq) * 4] = a2;                 \
        *(float4*)&(pp)[((ks) * 4 + 3) * 256 + (cq) * 4] = a3;                 \
    }

// ---------------- K1: QKV (raw input @ Wqkv + bias, de-interleave) ----------
// grid = 2 * 49 * 3 = 294 blocks (stream, token-tile of 4, col-group of 256)
__global__ __launch_bounds__(256) void k1_qkv(
    const float* __restrict__ vis, const float* __restrict__ ir,
    const float* __restrict__ Wqkv_v, const float* __restrict__ bqkv_v,
    const float* __restrict__ Wqkv_i, const float* __restrict__ bqkv_i,
    float* __restrict__ Q, float* __restrict__ Kq, float* __restrict__ Vq)
{
    const int b = blockIdx.x;
    const int s = b / 147;
    const int rem = b % 147;
    const int n0 = (rem / 3) * 4;
    const int cg = rem % 3;
    const int t = threadIdx.x;

    const float* x    = (s == 0) ? vis    : ir;
    const float* W    = (s == 0) ? Wqkv_v : Wqkv_i;
    const float* bias = (s == 0) ? bqkv_v : bqkv_i;

    __shared__ float xsT[EMB * 4];
    __shared__ float pp[4 * 4 * 256];

    {
        int r = t >> 6, c4 = (t & 63) * 4;
        float4 xv = *(const float4*)&x[(n0 + r) * EMB + c4];
        xsT[(c4 + 0) * 4 + r] = xv.x;
        xsT[(c4 + 1) * 4 + r] = xv.y;
        xsT[(c4 + 2) * 4 + r] = xv.z;
        xsT[(c4 + 3) * 4 + r] = xv.w;
    }
    __syncthreads();

    const int cq = t & 63, ks = t >> 6;
    GEMM_PANEL(W + cg * 256 + cq * 4, 768, xsT, pp, cq, ks, 64);
    __syncthreads();

    const int col = cg * 256 + t;
    const int h = col / 96, rr = col % 96, d = rr / 3, q = rr % 3;
    float* dst = (q == 0) ? Q : (q == 1 ? Kq : Vq);
    const float bval = bias[col];
    #pragma unroll
    for (int r = 0; r < 4; r++) {
        float v = pp[(0 * 4 + r) * 256 + t] + pp[(1 * 4 + r) * 256 + t]
                + pp[(2 * 4 + r) * 256 + t] + pp[(3 * 4 + r) * 256 + t] + bval;
        dst[((s * NH + h) * NT + n0 + r) * DH + d] = v;
    }
}

// ---------------- K2: cross-attention ----------------
// grid = 2*8*14 = 224 blocks (stream, head, 14-row tile). 256 threads = 4 waves.
__global__ __launch_bounds__(256) void k2_attn(
    const float* __restrict__ Q, const float* __restrict__ Kq,
    const float* __restrict__ Vq, float* __restrict__ AO)
{
    const int b  = blockIdx.x;
    const int s  = b / 112;
    const int rm = b % 112;
    const int h  = rm / 14;
    const int rt = rm % 14;
    const int t    = threadIdx.x;
    const int wv   = t >> 6;
    const int lane = t & 63;

    __shared__ float kl[NT * 33];
    __shared__ float vl[NT * 33];
    __shared__ float pb[4][NT];

    const float4* Ks4 = (const float4*)(Kq + ((1 - s) * NH + h) * NT * DH);
    const float4* Vs4 = (const float4*)(Vq + ((1 - s) * NH + h) * NT * DH);
    for (int idx = t; idx < NT * 8; idx += 256) {
        int j = idx >> 3, d4 = (idx & 7) * 4;
        float4 kv = Ks4[idx];
        kl[j * 33 + d4 + 0] = kv.x; kl[j * 33 + d4 + 1] = kv.y;
        kl[j * 33 + d4 + 2] = kv.z; kl[j * 33 + d4 + 3] = kv.w;
        float4 vv = Vs4[idx];
        vl[j * 33 + d4 + 0] = vv.x; vl[j * 33 + d4 + 1] = vv.y;
        vl[j * 33 + d4 + 2] = vv.z; vl[j * 33 + d4 + 3] = vv.w;
    }
    __syncthreads();

    const float* Qs = Q + ((s * NH + h) * NT) * DH;
    const bool v3 = (lane + 192) < NT;
    const int  j3 = v3 ? (lane + 192) : 0;

    for (int it = 0; it < 4; it++) {
        int lr = it * 4 + wv;
        bool act = lr < 14;
        int i = rt * 14 + lr;
        float inv_sum = 0.0f;
        if (act) {
            float qreg[DH];
            #pragma unroll
            for (int d = 0; d < DH; d++) qreg[d] = Qs[i * DH + d];
            float s0 = 0.f, s1 = 0.f, s2 = 0.f, s3 = 0.f;
            #pragma unroll
            for (int d = 0; d < DH; d++) {
                float qd = qreg[d];
                s0 = fmaf(qd, kl[(lane      ) * 33 + d], s0);
                s1 = fmaf(qd, kl[(lane +  64) * 33 + d], s1);
                s2 = fmaf(qd, kl[(lane + 128) * 33 + d], s2);
                s3 = fmaf(qd, kl[ j3          * 33 + d], s3);
            }
            const float sc = 1.0f / 16.0f;
            s0 *= sc; s1 *= sc; s2 *= sc; s3 *= sc;
            float m = fmaxf(fmaxf(s0, s1), v3 ? fmaxf(s2, s3) : s2);
            #pragma unroll
            for (int mk = 32; mk >= 1; mk >>= 1) m = fmaxf(m, __shfl_xor(m, mk));
            float p0 = expf(s0 - m), p1 = expf(s1 - m), p2 = expf(s2 - m);
            float p3 = v3 ? expf(s3 - m) : 0.0f;
            float ls = p0 + p1 + p2 + p3;
            #pragma unroll
            for (int mk = 32; mk >= 1; mk >>= 1) ls += __shfl_xor(ls, mk);
            inv_sum = 1.0f / ls;
            pb[wv][lane]       = p0;
            pb[wv][lane +  64] = p1;
            pb[wv][lane + 128] = p2;
            if (v3) pb[wv][lane + 192] = p3;
        }
        __syncthreads();
        if (act) {
            int d = lane & 31, half = lane >> 5;
            float o = 0.0f;
            int jb = half * 98;
            for (int jj = 0; jj < 98; jj++) {
                int j = jb + jj;
                o = fmaf(pb[wv][j], vl[j * 33 + d], o);
            }
            o += __shfl_xor(o, 32);
            if (lane < 32) AO[(s * NT + i) * EMB + h * DH + d] = o * inv_sum;
        }
        __syncthreads();
    }
}

// ---- K4: proj + LN1-res + LN2 (dup x4) + FFN1-strip + GELU + FFN2-partial --
// grid = 2 * 49 * 4 = 392 blocks (stream, token-tile of 4, HID-strip of 256).
// Strip-0 blocks also write LV (LN2 out) for k5's residual.
// P layout: [strip][ (s*NT+n) * EMB + col ]  (coalesced)
__global__ __launch_bounds__(256) void k4_ffn(
    const float* __restrict__ vis, const float* __restrict__ ir,
    const float* __restrict__ AO,
    const float* __restrict__ ln1v_w, const float* __restrict__ ln1v_b,
    const float* __restrict__ ln1i_w, const float* __restrict__ ln1i_b,
    const float* __restrict__ Wp_v, const float* __restrict__ bp_v,
    const float* __restrict__ Wp_i, const float* __restrict__ bp_i,
    const float* __restrict__ ln2v_w, const float* __restrict__ ln2v_b,
    const float* __restrict__ ln2i_w, const float* __restrict__ ln2i_b,
    const float* __restrict__ W1v, const float* __restrict__ b1v,
    const float* __restrict__ W1i, const float* __restrict__ b1i,
    const float* __restrict__ W2v, const float* __restrict__ W2i,
    float* __restrict__ LV, float* __restrict__ P)
{
    const int b = blockIdx.x;
    const int s = b / 196;
    const int rem = b % 196;
    const int n0 = (rem / 4) * 4;
    const int strip = rem % 4;
    const int col0 = strip * 256;
    const int t = threadIdx.x;

    const float* x   = (s == 0) ? vis    : ir;
    const float* Wp  = (s == 0) ? Wp_v   : Wp_i;
    const float* bp  = (s == 0) ? bp_v   : bp_i;
    const float* l1w = (s == 0) ? ln1v_w : ln1i_w;
    const float* l1b = (s == 0) ? ln1v_b : ln1i_b;
    const float* l2w = (s == 0) ? ln2v_w : ln2i_w;
    const float* l2b = (s == 0) ? ln2v_b : ln2i_b;
    const float* W1  = (s == 0) ? W1v    : W1i;
    const float* bb1 = (s == 0) ? b1v    : b1i;
    const float* W2  = (s == 0) ? W2v    : W2i;

    __shared__ float aoT[EMB * 4];       // 4 KB (reused as lvT after LN2)
    __shared__ float nvb[4 * 256];       // 4 KB
    __shared__ float rbuf[4 * 256];      // 4 KB (reused as hhT)
    __shared__ float pp[4 * 4 * 256];    // 16 KB

    const int r = t >> 6, lane = t & 63, c4 = lane * 4;
    const int cq = t & 63, ks = t >> 6;

    // Phase A: LN1(x) + AO transpose (wave r = token r)
    {
        float4 xv = *(const float4*)&x[(n0 + r) * EMB + c4];
        float sum = xv.x + xv.y + xv.z + xv.w;
        float sq  = xv.x*xv.x + xv.y*xv.y + xv.z*xv.z + xv.w*xv.w;
        #pragma unroll
        for (int mk = 32; mk >= 1; mk >>= 1) {
            sum += __shfl_xor(sum, mk);
            sq  += __shfl_xor(sq,  mk);
        }
        float mean = sum * (1.0f / EMB);
        float inv  = rsqrtf(sq * (1.0f / EMB) - mean * mean + EPSV);
        float4 wv4 = *(const float4*)&l1w[c4];
        float4 bv4 = *(const float4*)&l1b[c4];
        nvb[r * 256 + c4 + 0] = (xv.x - mean) * inv * wv4.x + bv4.x;
        nvb[r * 256 + c4 + 1] = (xv.y - mean) * inv * wv4.y + bv4.y;
        nvb[r * 256 + c4 + 2] = (xv.z - mean) * inv * wv4.z + bv4.z;
        nvb[r * 256 + c4 + 3] = (xv.w - mean) * inv * wv4.w + bv4.w;
        float4 av = *(const float4*)&AO[(s * NT + n0 + r) * EMB + c4];
        aoT[(c4 + 0) * 4 + r] = av.x;
        aoT[(c4 + 1) * 4 + r] = av.y;
        aoT[(c4 + 2) * 4 + r] = av.z;
        aoT[(c4 + 3) * 4 + r] = av.w;
    }
    __syncthreads();

    // Phase B: proj GEMM (full 256 cols, needed for LN2)
    GEMM_PANEL(Wp + cq * 4, EMB, aoT, pp, cq, ks, 64);
    __syncthreads();
    {
        const float bval = bp[t];
        #pragma unroll
        for (int r2 = 0; r2 < 4; r2++) {
            float v = pp[(0 * 4 + r2) * 256 + t] + pp[(1 * 4 + r2) * 256 + t]
                    + pp[(2 * 4 + r2) * 256 + t] + pp[(3 * 4 + r2) * 256 + t]
                    + bval + nvb[r2 * 256 + t];
            rbuf[r2 * 256 + t] = v;
        }
    }
    __syncthreads();

    // Phase C: LN2 -> lvT (transposed, in aoT's slot) (+ LV global if strip 0)
    {
        float4 rv = *(const float4*)&rbuf[r * 256 + c4];
        float sum = rv.x + rv.y + rv.z + rv.w;
        float sq  = rv.x*rv.x + rv.y*rv.y + rv.z*rv.z + rv.w*rv.w;
        #pragma unroll
        for (int mk = 32; mk >= 1; mk >>= 1) {
            sum += __shfl_xor(sum, mk);
            sq  += __shfl_xor(sq,  mk);
        }
        float mean = sum * (1.0f / EMB);
        float inv  = rsqrtf(sq * (1.0f / EMB) - mean * mean + EPSV);
        float4 wv4 = *(const float4*)&l2w[c4];
        float4 bv4 = *(const float4*)&l2b[c4];
        float4 o;
        o.x = (rv.x - mean) * inv * wv4.x + bv4.x;
        o.y = (rv.y - mean) * inv * wv4.y + bv4.y;
        o.z = (rv.z - mean) * inv * wv4.z + bv4.z;
        o.w = (rv.w - mean) * inv * wv4.w + bv4.w;
        __syncthreads();                 // rbuf reads done before aoT reuse?
        // (aoT and rbuf are distinct buffers; barrier orders aoT overwrite
        //  after Phase B's aoT reads -- GEMM already done, but lvT aliases aoT)
        aoT[(c4 + 0) * 4 + r] = o.x;
        aoT[(c4 + 1) * 4 + r] = o.y;
        aoT[(c4 + 2) * 4 + r] = o.z;
        aoT[(c4 + 3) * 4 + r] = o.w;
        if (strip == 0)
            *(float4*)&LV[(s * NT + n0 + r) * EMB + c4] = o;
    }
    __syncthreads();

    // Phase D: FFN1 strip (256 cols of HID, K=256) from lvT (= aoT)
    GEMM_PANEL(W1 + col0 + cq * 4, HID, aoT, pp, cq, ks, 64);
    __syncthreads();
    {
        const float bval = bb1[col0 + t];
        const float kg = 0.7071067811865475f;
        float4 h;
        #pragma unroll
        for (int r2 = 0; r2 < 4; r2++) {
            float v = pp[(0 * 4 + r2) * 256 + t] + pp[(1 * 4 + r2) * 256 + t]
                    + pp[(2 * 4 + r2) * 256 + t] + pp[(3 * 4 + r2) * 256 + t] + bval;
            ((float*)&h)[r2] = 0.5f * v * (1.0f + erff(v * kg));
        }
        __syncthreads();                 // pp reads done before hhT (rbuf) write
        *(float4*)&rbuf[t * 4] = h;      // hhT[col][4] in rbuf's slot
    }
    __syncthreads();

    // Phase E: FFN2 partial (rows col0..col0+255 of W2) from hhT (= rbuf)
    GEMM_PANEL(W2 + col0 * EMB + cq * 4, EMB, rbuf, pp, cq, ks, 64);
    __syncthreads();
    {
        float* Pd = P + (size_t)strip * (2 * NT * EMB);
        #pragma unroll
        for (int r2 = 0; r2 < 4; r2++) {
            float v = pp[(0 * 4 + r2) * 256 + t] + pp[(1 * 4 + r2) * 256 + t]
                    + pp[(2 * 4 + r2) * 256 + t] + pp[(3 * 4 + r2) * 256 + t];
            Pd[(s * NT + n0 + r2) * EMB + t] = v;
        }
    }
}

// ---------------- K5: out = sum(P) + LV + b2, scattered recon ---------------
// grid = 2 * 49 = 98 blocks (4-token tiles)
__global__ __launch_bounds__(256) void k5_reduce(
    const float* __restrict__ P, const float* __restrict__ LV,
    const float* __restrict__ b2v, const float* __restrict__ b2i,
    float* __restrict__ out)
{
    const int b = blockIdx.x;
    const int s = b / 49;
    const int n0 = (b % 49) * 4;
    const int t = threadIdx.x;
    const float* bb2 = (s == 0) ? b2v : b2i;

    const float bval = bb2[t];
    const int p1 = t >> 4, p2 = t & 15;
    const int ch = (s == 0) ? 1 : 0;   // channel 0 = ir, 1 = vis
    const size_t SP = (size_t)2 * NT * EMB;
    #pragma unroll
    for (int r = 0; r < 4; r++) {
        int n = n0 + r;
        size_t base = (size_t)(s * NT + n) * EMB + t;
        float v = P[base] + P[SP + base] + P[2 * SP + base] + P[3 * SP + base]
                + LV[base] + bval;
        int n1 = n / 14, n2 = n % 14;
        int f = p1 * 3136 + p2 * 196 + n1 * 14 + n2;
        out[ch * 50176 + f] = v;
    }
}

extern "C" void kernel_launch(void* const* d_in, const int* in_sizes, int n_in,
                              void* d_out, int out_size, void* d_ws, size_t ws_size,
                              hipStream_t stream)
{
    const float* vis    = (const float*)d_in[0];
    const float* ir     = (const float*)d_in[1];
    const float* ln1v_w = (const float*)d_in[2];
    const float* ln1v_b = (const float*)d_in[3];
    const float* ln1i_w = (const float*)d_in[4];
    const float* ln1i_b = (const float*)d_in[5];
    const float* ln2v_w = (const float*)d_in[6];
    const float* ln2v_b = (const float*)d_in[7];
    const float* ln2i_w = (const float*)d_in[8];
    const float* ln2i_b = (const float*)d_in[9];
    const float* Wqkv_v = (const float*)d_in[10];
    const float* bqkv_v = (const float*)d_in[11];
    const float* Wqkv_i = (const float*)d_in[12];
    const float* bqkv_i = (const float*)d_in[13];
    const float* Wp_v   = (const float*)d_in[14];
    const float* bp_v   = (const float*)d_in[15];
    const float* Wp_i   = (const float*)d_in[16];
    const float* bp_i   = (const float*)d_in[17];
    const float* W1v    = (const float*)d_in[18];
    const float* b1v    = (const float*)d_in[19];
    const float* W2v    = (const float*)d_in[20];
    const float* b2v    = (const float*)d_in[21];
    const float* W1i    = (const float*)d_in[22];
    const float* b1i    = (const float*)d_in[23];
    const float* W2i    = (const float*)d_in[24];
    const float* b2i    = (const float*)d_in[25];

    float* ws = (float*)d_ws;
    float* Q  = ws;               // [2][8][196][32]   100352
    float* K  = ws + 100352;
    float* V  = ws + 200704;
    float* AO = ws + 301056;      // [2][196][256]     100352
    float* LV = ws + 401408;      // [2][196][256]     100352
    float* P  = ws + 501760;      // [4][2][196][256]  401408

    k1_qkv<<<294, 256, 0, stream>>>(vis, ir, Wqkv_v, bqkv_v, Wqkv_i, bqkv_i, Q, K, V);
    k2_attn<<<224, 256, 0, stream>>>(Q, K, V, AO);
    k4_ffn<<<392, 256, 0, stream>>>(vis, ir, AO,
                                    ln1v_w, ln1v_b, ln1i_w, ln1i_b,
                                    Wp_v, bp_v, Wp_i, bp_i,
                                    ln2v_w, ln2v_b, ln2i_w, ln2i_b,
                                    W1v, b1v, W1i, b1i, W2v, W2i, LV, P);
    k5_reduce<<<98, 256, 0, stream>>>(P, LV, b2v, b2i, (float*)d_out);
}

// Round 9
// 161.014 us; speedup vs baseline: 1.0417x; 1.0417x over previous
//
#include <hip/hip_runtime.h>
#include <math.h>

#define NT   196
#define EMB  256
#define NH   8
#define DH   32
#define HID  1024
#define EPSV 1e-5f

// 4x4-register-blocked K-panel: 1 float4 W load + 1 broadcast b128 X read +
// 16 fma per iter. Threads: cq = t&63 (col quad), ks = t>>6 (K split of 4).
// unroll 8: measured best (R7=161.3us); unroll 16 gave no extra in-flight
// loads (VGPR stayed 68) and regressed when combined with fusion (R8).
#define GEMM_PANEL(Wptr, ldw, xsT, pp, cq, ks, KITER)                          \
    {                                                                          \
        const float* Wb = (Wptr);                                              \
        float4 a0 = {0,0,0,0}, a1 = a0, a2 = a0, a3 = a0;                      \
        _Pragma("unroll 8")                                                    \
        for (int kk = (ks) * (KITER); kk < (ks) * (KITER) + (KITER); kk++) {   \
            float4 w4 = *(const float4*)&Wb[kk * (ldw)];                       \
            float4 xr = *(const float4*)&(xsT)[kk * 4];                        \
            a0.x = fmaf(xr.x, w4.x, a0.x); a0.y = fmaf(xr.x, w4.y, a0.y);      \
            a0.z = fmaf(xr.x, w4.z, a0.z); a0.w = fmaf(xr.x, w4.w, a0.w);      \
            a1.x = fmaf(xr.y, w4.x, a1.x); a1.y = fmaf(xr.y, w4.y, a1.y);      \
            a1.z = fmaf(xr.y, w4.z, a1.z); a1.w = fmaf(xr.y, w4.w, a1.w);      \
            a2.x = fmaf(xr.z, w4.x, a2.x); a2.y = fmaf(xr.z, w4.y, a2.y);      \
            a2.z = fmaf(xr.z, w4.z, a2.z); a2.w = fmaf(xr.z, w4.w, a2.w);      \
            a3.x = fmaf(xr.w, w4.x, a3.x); a3.y = fmaf(xr.w, w4.y, a3.y);      \
            a3.z = fmaf(xr.w, w4.z, a3.z); a3.w = fmaf(xr.w, w4.w, a3.w);      \
        }                                                                      \
        *(float4*)&(pp)[((ks) * 4 + 0) * 256 + (cq) * 4] = a0;                 \
        *(float4*)&(pp)[((ks) * 4 + 1) * 256 + (cq) * 4] = a1;                 \
        *(float4*)&(pp)[((ks) * 4 + 2) * 256 + (cq) * 4] = a2;                 \
        *(float4*)&(pp)[((ks) * 4 + 3) * 256 + (cq) * 4] = a3;                 \
    }

// ---------------- K1: QKV (raw input @ Wqkv + bias, de-interleave) ----------
// grid = 2 * 49 * 3 = 294 blocks (stream, token-tile of 4, col-group of 256)
__global__ __launch_bounds__(256) void k1_qkv(
    const float* __restrict__ vis, const float* __restrict__ ir,
    const float* __restrict__ Wqkv_v, const float* __restrict__ bqkv_v,
    const float* __restrict__ Wqkv_i, const float* __restrict__ bqkv_i,
    float* __restrict__ Q, float* __restrict__ Kq, float* __restrict__ Vq)
{
    const int b = blockIdx.x;
    const int s = b / 147;
    const int rem = b % 147;
    const int n0 = (rem / 3) * 4;
    const int cg = rem % 3;
    const int t = threadIdx.x;

    const float* x    = (s == 0) ? vis    : ir;
    const float* W    = (s == 0) ? Wqkv_v : Wqkv_i;
    const float* bias = (s == 0) ? bqkv_v : bqkv_i;

    __shared__ float xsT[EMB * 4];
    __shared__ float pp[4 * 4 * 256];

    {
        int r = t >> 6, c4 = (t & 63) * 4;
        float4 xv = *(const float4*)&x[(n0 + r) * EMB + c4];
        xsT[(c4 + 0) * 4 + r] = xv.x;
        xsT[(c4 + 1) * 4 + r] = xv.y;
        xsT[(c4 + 2) * 4 + r] = xv.z;
        xsT[(c4 + 3) * 4 + r] = xv.w;
    }
    __syncthreads();

    const int cq = t & 63, ks = t >> 6;
    GEMM_PANEL(W + cg * 256 + cq * 4, 768, xsT, pp, cq, ks, 64);
    __syncthreads();

    const int col = cg * 256 + t;
    const int h = col / 96, rr = col % 96, d = rr / 3, q = rr % 3;
    float* dst = (q == 0) ? Q : (q == 1 ? Kq : Vq);
    const float bval = bias[col];
    #pragma unroll
    for (int r = 0; r < 4; r++) {
        float v = pp[(0 * 4 + r) * 256 + t] + pp[(1 * 4 + r) * 256 + t]
                + pp[(2 * 4 + r) * 256 + t] + pp[(3 * 4 + r) * 256 + t] + bval;
        dst[((s * NH + h) * NT + n0 + r) * DH + d] = v;
    }
}

// ---------------- K2: cross-attention ----------------
// grid = 2*8*14 = 224 blocks (stream, head, 14-row tile). 256 threads = 4 waves.
__global__ __launch_bounds__(256) void k2_attn(
    const float* __restrict__ Q, const float* __restrict__ Kq,
    const float* __restrict__ Vq, float* __restrict__ AO)
{
    const int b  = blockIdx.x;
    const int s  = b / 112;
    const int rm = b % 112;
    const int h  = rm / 14;
    const int rt = rm % 14;
    const int t    = threadIdx.x;
    const int wv   = t >> 6;
    const int lane = t & 63;

    __shared__ float kl[NT * 33];
    __shared__ float vl[NT * 33];
    __shared__ float pb[4][NT];

    const float4* Ks4 = (const float4*)(Kq + ((1 - s) * NH + h) * NT * DH);
    const float4* Vs4 = (const float4*)(Vq + ((1 - s) * NH + h) * NT * DH);
    for (int idx = t; idx < NT * 8; idx += 256) {
        int j = idx >> 3, d4 = (idx & 7) * 4;
        float4 kv = Ks4[idx];
        kl[j * 33 + d4 + 0] = kv.x; kl[j * 33 + d4 + 1] = kv.y;
        kl[j * 33 + d4 + 2] = kv.z; kl[j * 33 + d4 + 3] = kv.w;
        float4 vv = Vs4[idx];
        vl[j * 33 + d4 + 0] = vv.x; vl[j * 33 + d4 + 1] = vv.y;
        vl[j * 33 + d4 + 2] = vv.z; vl[j * 33 + d4 + 3] = vv.w;
    }
    __syncthreads();

    const float* Qs = Q + ((s * NH + h) * NT) * DH;
    const bool v3 = (lane + 192) < NT;
    const int  j3 = v3 ? (lane + 192) : 0;

    for (int it = 0; it < 4; it++) {
        int lr = it * 4 + wv;
        bool act = lr < 14;
        int i = rt * 14 + lr;
        float inv_sum = 0.0f;
        if (act) {
            float qreg[DH];
            #pragma unroll
            for (int d = 0; d < DH; d++) qreg[d] = Qs[i * DH + d];
            float s0 = 0.f, s1 = 0.f, s2 = 0.f, s3 = 0.f;
            #pragma unroll
            for (int d = 0; d < DH; d++) {
                float qd = qreg[d];
                s0 = fmaf(qd, kl[(lane      ) * 33 + d], s0);
                s1 = fmaf(qd, kl[(lane +  64) * 33 + d], s1);
                s2 = fmaf(qd, kl[(lane + 128) * 33 + d], s2);
                s3 = fmaf(qd, kl[ j3          * 33 + d], s3);
            }
            const float sc = 1.0f / 16.0f;
            s0 *= sc; s1 *= sc; s2 *= sc; s3 *= sc;
            float m = fmaxf(fmaxf(s0, s1), v3 ? fmaxf(s2, s3) : s2);
            #pragma unroll
            for (int mk = 32; mk >= 1; mk >>= 1) m = fmaxf(m, __shfl_xor(m, mk));
            float p0 = expf(s0 - m), p1 = expf(s1 - m), p2 = expf(s2 - m);
            float p3 = v3 ? expf(s3 - m) : 0.0f;
            float ls = p0 + p1 + p2 + p3;
            #pragma unroll
            for (int mk = 32; mk >= 1; mk >>= 1) ls += __shfl_xor(ls, mk);
            inv_sum = 1.0f / ls;
            pb[wv][lane]       = p0;
            pb[wv][lane +  64] = p1;
            pb[wv][lane + 128] = p2;
            if (v3) pb[wv][lane + 192] = p3;
        }
        __syncthreads();
        if (act) {
            int d = lane & 31, half = lane >> 5;
            float o = 0.0f;
            int jb = half * 98;
            for (int jj = 0; jj < 98; jj++) {
                int j = jb + jj;
                o = fmaf(pb[wv][j], vl[j * 33 + d], o);
            }
            o += __shfl_xor(o, 32);
            if (lane < 32) AO[(s * NT + i) * EMB + h * DH + d] = o * inv_sum;
        }
        __syncthreads();
    }
}

// ---------------- K3: proj + LN1-res + LN2 -> LV ----------------
// grid = 2 * 49 = 98 blocks (4-token tiles)
__global__ __launch_bounds__(256) void k3_projln(
    const float* __restrict__ vis, const float* __restrict__ ir,
    const float* __restrict__ AO,
    const float* __restrict__ ln1v_w, const float* __restrict__ ln1v_b,
    const float* __restrict__ ln1i_w, const float* __restrict__ ln1i_b,
    const float* __restrict__ Wp_v, const float* __restrict__ bp_v,
    const float* __restrict__ Wp_i, const float* __restrict__ bp_i,
    const float* __restrict__ ln2v_w, const float* __restrict__ ln2v_b,
    const float* __restrict__ ln2i_w, const float* __restrict__ ln2i_b,
    float* __restrict__ LV)
{
    const int b = blockIdx.x;
    const int s = b / 49;
    const int n0 = (b % 49) * 4;
    const int t = threadIdx.x;

    const float* x   = (s == 0) ? vis    : ir;
    const float* Wp  = (s == 0) ? Wp_v   : Wp_i;
    const float* bp  = (s == 0) ? bp_v   : bp_i;
    const float* l1w = (s == 0) ? ln1v_w : ln1i_w;
    const float* l1b = (s == 0) ? ln1v_b : ln1i_b;
    const float* l2w = (s == 0) ? ln2v_w : ln2i_w;
    const float* l2b = (s == 0) ? ln2v_b : ln2i_b;

    __shared__ float aoT[EMB * 4];
    __shared__ float nvb[4 * 256];
    __shared__ float rbuf[4 * 256];
    __shared__ float pp[4 * 4 * 256];

    const int r = t >> 6, lane = t & 63, c4 = lane * 4;
    const int cq = t & 63, ks = t >> 6;

    // Phase A: LN1(x) + AO transpose (wave r = token r)
    {
        float4 xv = *(const float4*)&x[(n0 + r) * EMB + c4];
        float sum = xv.x + xv.y + xv.z + xv.w;
        float sq  = xv.x*xv.x + xv.y*xv.y + xv.z*xv.z + xv.w*xv.w;
        #pragma unroll
        for (int mk = 32; mk >= 1; mk >>= 1) {
            sum += __shfl_xor(sum, mk);
            sq  += __shfl_xor(sq,  mk);
        }
        float mean = sum * (1.0f / EMB);
        float inv  = rsqrtf(sq * (1.0f / EMB) - mean * mean + EPSV);
        float4 wv4 = *(const float4*)&l1w[c4];
        float4 bv4 = *(const float4*)&l1b[c4];
        nvb[r * 256 + c4 + 0] = (xv.x - mean) * inv * wv4.x + bv4.x;
        nvb[r * 256 + c4 + 1] = (xv.y - mean) * inv * wv4.y + bv4.y;
        nvb[r * 256 + c4 + 2] = (xv.z - mean) * inv * wv4.z + bv4.z;
        nvb[r * 256 + c4 + 3] = (xv.w - mean) * inv * wv4.w + bv4.w;
        float4 av = *(const float4*)&AO[(s * NT + n0 + r) * EMB + c4];
        aoT[(c4 + 0) * 4 + r] = av.x;
        aoT[(c4 + 1) * 4 + r] = av.y;
        aoT[(c4 + 2) * 4 + r] = av.z;
        aoT[(c4 + 3) * 4 + r] = av.w;
    }
    __syncthreads();

    // Phase B: proj GEMM
    GEMM_PANEL(Wp + cq * 4, EMB, aoT, pp, cq, ks, 64);
    __syncthreads();

    // Phase C: residual + LN2 -> LV (coalesced)
    {
        const float bval = bp[t];
        #pragma unroll
        for (int r2 = 0; r2 < 4; r2++) {
            float v = pp[(0 * 4 + r2) * 256 + t] + pp[(1 * 4 + r2) * 256 + t]
                    + pp[(2 * 4 + r2) * 256 + t] + pp[(3 * 4 + r2) * 256 + t]
                    + bval + nvb[r2 * 256 + t];
            rbuf[r2 * 256 + t] = v;
        }
    }
    __syncthreads();
    {
        float4 rv = *(const float4*)&rbuf[r * 256 + c4];
        float sum = rv.x + rv.y + rv.z + rv.w;
        float sq  = rv.x*rv.x + rv.y*rv.y + rv.z*rv.z + rv.w*rv.w;
        #pragma unroll
        for (int mk = 32; mk >= 1; mk >>= 1) {
            sum += __shfl_xor(sum, mk);
            sq  += __shfl_xor(sq,  mk);
        }
        float mean = sum * (1.0f / EMB);
        float inv  = rsqrtf(sq * (1.0f / EMB) - mean * mean + EPSV);
        float4 wv4 = *(const float4*)&l2w[c4];
        float4 bv4 = *(const float4*)&l2b[c4];
        float4 o;
        o.x = (rv.x - mean) * inv * wv4.x + bv4.x;
        o.y = (rv.y - mean) * inv * wv4.y + bv4.y;
        o.z = (rv.z - mean) * inv * wv4.z + bv4.z;
        o.w = (rv.w - mean) * inv * wv4.w + bv4.w;
        *(float4*)&LV[(s * NT + n0 + r) * EMB + c4] = o;
    }
}

// ---------------- K4: FFN1-strip + GELU + FFN2-partial -> P (coalesced) -----
// grid = 2 * 49 * 4 = 392 blocks (stream, token-tile of 4, HID-strip of 256).
// P layout: [strip][ (s*NT+n) * EMB + col ]  (float4 coalesced writes)
__global__ __launch_bounds__(256) void k4_ffn(
    const float* __restrict__ LV,
    const float* __restrict__ W1v, const float* __restrict__ b1v,
    const float* __restrict__ W1i, const float* __restrict__ b1i,
    const float* __restrict__ W2v, const float* __restrict__ W2i,
    float* __restrict__ P)
{
    const int b = blockIdx.x;
    const int s = b / 196;
    const int rem = b % 196;
    const int n0 = (rem / 4) * 4;
    const int strip = rem % 4;
    const int col0 = strip * 256;       // HID strip
    const int t = threadIdx.x;

    const float* W1  = (s == 0) ? W1v : W1i;
    const float* bb1 = (s == 0) ? b1v : b1i;
    const float* W2  = (s == 0) ? W2v : W2i;

    __shared__ float lvT[EMB * 4];
    __shared__ float hhT[256 * 4];
    __shared__ float pp[4 * 4 * 256];

    // load LN2 output tile, transposed
    {
        int r = t >> 6, c4 = (t & 63) * 4;
        float4 xv = *(const float4*)&LV[(s * NT + n0 + r) * EMB + c4];
        lvT[(c4 + 0) * 4 + r] = xv.x;
        lvT[(c4 + 1) * 4 + r] = xv.y;
        lvT[(c4 + 2) * 4 + r] = xv.z;
        lvT[(c4 + 3) * 4 + r] = xv.w;
    }
    __syncthreads();

    const int cq = t & 63, ks = t >> 6;

    // FFN1 strip: 256 cols of HID, K=256
    GEMM_PANEL(W1 + col0 + cq * 4, HID, lvT, pp, cq, ks, 64);
    __syncthreads();

    // bias + GELU -> hhT[col][4]
    {
        const float bval = bb1[col0 + t];
        const float kg = 0.7071067811865475f;
        float4 h;
        #pragma unroll
        for (int r = 0; r < 4; r++) {
            float v = pp[(0 * 4 + r) * 256 + t] + pp[(1 * 4 + r) * 256 + t]
                    + pp[(2 * 4 + r) * 256 + t] + pp[(3 * 4 + r) * 256 + t] + bval;
            ((float*)&h)[r] = 0.5f * v * (1.0f + erff(v * kg));
        }
        *(float4*)&hhT[t * 4] = h;
    }
    __syncthreads();

    // FFN2 partial: rows col0..col0+255 of W2, all 256 out cols
    GEMM_PANEL(W2 + col0 * EMB + cq * 4, EMB, hhT, pp, cq, ks, 64);
    __syncthreads();

    // reduce K-splits, write partials coalesced
    {
        float* Pd = P + (size_t)strip * (2 * NT * EMB);
        #pragma unroll
        for (int r = 0; r < 4; r++) {
            float v = pp[(0 * 4 + r) * 256 + t] + pp[(1 * 4 + r) * 256 + t]
                    + pp[(2 * 4 + r) * 256 + t] + pp[(3 * 4 + r) * 256 + t];
            Pd[(s * NT + n0 + r) * EMB + t] = v;
        }
    }
}

// ---------------- K5: out = sum(P) + LV + b2, scattered recon ---------------
// grid = 2 * 49 = 98 blocks (4-token tiles)
__global__ __launch_bounds__(256) void k5_reduce(
    const float* __restrict__ P, const float* __restrict__ LV,
    const float* __restrict__ b2v, const float* __restrict__ b2i,
    float* __restrict__ out)
{
    const int b = blockIdx.x;
    const int s = b / 49;
    const int n0 = (b % 49) * 4;
    const int t = threadIdx.x;
    const float* bb2 = (s == 0) ? b2v : b2i;

    const float bval = bb2[t];
    const int p1 = t >> 4, p2 = t & 15;
    const int ch = (s == 0) ? 1 : 0;   // channel 0 = ir, 1 = vis
    const size_t SP = (size_t)2 * NT * EMB;
    #pragma unroll
    for (int r = 0; r < 4; r++) {
        int n = n0 + r;
        size_t base = (size_t)(s * NT + n) * EMB + t;
        float v = P[base] + P[SP + base] + P[2 * SP + base] + P[3 * SP + base]
                + LV[base] + bval;
        int n1 = n / 14, n2 = n % 14;
        int f = p1 * 3136 + p2 * 196 + n1 * 14 + n2;
        out[ch * 50176 + f] = v;
    }
}

extern "C" void kernel_launch(void* const* d_in, const int* in_sizes, int n_in,
                              void* d_out, int out_size, void* d_ws, size_t ws_size,
                              hipStream_t stream)
{
    const float* vis    = (const float*)d_in[0];
    const float* ir     = (const float*)d_in[1];
    const float* ln1v_w = (const float*)d_in[2];
    const float* ln1v_b = (const float*)d_in[3];
    const float* ln1i_w = (const float*)d_in[4];
    const float* ln1i_b = (const float*)d_in[5];
    const float* ln2v_w = (const float*)d_in[6];
    const float* ln2v_b = (const float*)d_in[7];
    const float* ln2i_w = (const float*)d_in[8];
    const float* ln2i_b = (const float*)d_in[9];
    const float* Wqkv_v = (const float*)d_in[10];
    const float* bqkv_v = (const float*)d_in[11];
    const float* Wqkv_i = (const float*)d_in[12];
    const float* bqkv_i = (const float*)d_in[13];
    const float* Wp_v   = (const float*)d_in[14];
    const float* bp_v   = (const float*)d_in[15];
    const float* Wp_i   = (const float*)d_in[16];
    const float* bp_i   = (const float*)d_in[17];
    const float* W1v    = (const float*)d_in[18];
    const float* b1v    = (const float*)d_in[19];
    const float* W2v    = (const float*)d_in[20];
    const float* b2v    = (const float*)d_in[21];
    const float* W1i    = (const float*)d_in[22];
    const float* b1i    = (const float*)d_in[23];
    const float* W2i    = (const float*)d_in[24];
    const float* b2i    = (const float*)d_in[25];

    float* ws = (float*)d_ws;
    float* Q  = ws;               // [2][8][196][32]   100352
    float* K  = ws + 100352;
    float* V  = ws + 200704;
    float* AO = ws + 301056;      // [2][196][256]     100352
    float* LV = ws + 401408;      // [2][196][256]     100352
    float* P  = ws + 501760;      // [4][2][196][256]  401408

    k1_qkv<<<294, 256, 0, stream>>>(vis, ir, Wqkv_v, bqkv_v, Wqkv_i, bqkv_i, Q, K, V);
    k2_attn<<<224, 256, 0, stream>>>(Q, K, V, AO);
    k3_projln<<<98, 256, 0, stream>>>(vis, ir, AO,
                                      ln1v_w, ln1v_b, ln1i_w, ln1i_b,
                                      Wp_v, bp_v, Wp_i, bp_i,
                                      ln2v_w, ln2v_b, ln2i_w, ln2i_b, LV);
    k4_ffn<<<392, 256, 0, stream>>>(LV, W1v, b1v, W1i, b1i, W2v, W2i, P);
    k5_reduce<<<98, 256, 0, stream>>>(P, LV, b2v, b2i, (float*)d_out);
}